// Round 1
// baseline (1440.261 us; speedup 1.0000x reference)
//
#include <hip/hip_runtime.h>

// ---------------------------------------------------------------------------
// Elastic 2D velocity-stress staggered-grid FD with C-PML, 2 shots, 128 steps.
// Round 1: correctness-first baseline. 2 kernels per time step (velocity,
// stress), all state in global memory (fits in L2: ~12 MB), padded pitch for
// coalescing. Receivers gathered in the stress kernel; source injected by the
// owning thread in the velocity kernel.
// ---------------------------------------------------------------------------

#define NYI   300
#define NXI   300
#define PML   20
#define NYP   340            // NYI + 2*PML
#define NXP   340
#define NT    128
#define DXC   5.0f
#define DTC   0.001f
#define NSHOT 2
#define NSRC  1
#define NREC  32
#define C1C   (9.0f / 8.0f)
#define C2C   (-1.0f / 24.0f)
#define RDX   (1.0f / 5.0f)  // 1/DX

#define PITCH   352                 // row pitch in floats (128B-aligned rows)
#define FSTRIDE (NYP * PITCH)       // floats per field = 119680

// per-shot field order in workspace:
// 0 vy, 1 vx, 2 syy, 3 sxx, 4 sxy,
// 5 mvyy, 6 mvyx, 7 mvxy, 8 mvxx, 9 msyy_y, 10 msxy_x, 11 msxy_y, 12 msxx_x

__device__ __forceinline__ float ldf(const float* f, int y, int x) {
    return (y >= 0 && y < NYP && x >= 0 && x < NXP) ? f[y * PITCH + x] : 0.0f;
}

// 4th-order staggered derivatives, zero-padded boundary semantics (match jnp.pad)
__device__ __forceinline__ float dpy(const float* f, int y, int x) {
    return (C1C * (ldf(f, y + 1, x) - ldf(f, y, x)) +
            C2C * (ldf(f, y + 2, x) - ldf(f, y - 1, x))) * RDX;
}
__device__ __forceinline__ float dmy(const float* f, int y, int x) {
    return (C1C * (ldf(f, y, x) - ldf(f, y - 1, x)) +
            C2C * (ldf(f, y + 1, x) - ldf(f, y - 2, x))) * RDX;
}
__device__ __forceinline__ float dpx(const float* f, int y, int x) {
    return (C1C * (ldf(f, y, x + 1) - ldf(f, y, x)) +
            C2C * (ldf(f, y, x + 2) - ldf(f, y, x - 1))) * RDX;
}
__device__ __forceinline__ float dmx(const float* f, int y, int x) {
    return (C1C * (ldf(f, y, x) - ldf(f, y, x - 1)) +
            C2C * (ldf(f, y, x + 1) - ldf(f, y, x - 2))) * RDX;
}

// Edge-pad model params into workspace: params[0]=lam, [1]=lam+2mu, [2]=mu, [3]=buoyancy
__global__ void init_params_kernel(const float* __restrict__ lamb,
                                   const float* __restrict__ mu,
                                   const float* __restrict__ buo,
                                   float* __restrict__ params) {
    int x = blockIdx.x * blockDim.x + threadIdx.x;
    int y = blockIdx.y;
    if (x >= NXP || y >= NYP) return;
    int cy = y - PML; cy = cy < 0 ? 0 : (cy > NYI - 1 ? NYI - 1 : cy);
    int cx = x - PML; cx = cx < 0 ? 0 : (cx > NXI - 1 ? NXI - 1 : cx);
    float l = lamb[cy * NXI + cx];
    float m = mu[cy * NXI + cx];
    float b = buo[cy * NXI + cx];
    int idx = y * PITCH + x;
    params[0 * FSTRIDE + idx] = l;
    params[1 * FSTRIDE + idx] = l + 2.0f * m;
    params[2 * FSTRIDE + idx] = m;
    params[3 * FSTRIDE + idx] = b;
}

// C-PML decay factors: bdec[0..NYP) = by, bdec[NYP..NYP+NXP) = bx
__global__ void init_decay_kernel(float* __restrict__ bdec) {
    int i = blockIdx.x * blockDim.x + threadIdx.x;
    if (i >= NYP + NXP) return;
    int idx = (i < NYP) ? i : i - NYP;   // NYP == NXP so same profile
    float fx = (float)idx;
    float lo = fminf(fmaxf(((float)PML - fx) / (float)PML, 0.0f), 1.0f);
    float hi = fminf(fmaxf((fx - (float)(NYP - 1 - PML)) / (float)PML, 0.0f), 1.0f);
    float mx = fmaxf(lo, hi);
    float d0 = 3.0f * 2000.0f / (2.0f * (float)PML * DXC) * logf(1.0f / 1e-6f);
    float sig = d0 * mx * mx;
    bdec[i] = expf(-sig * DTC);
}

__global__ __launch_bounds__(256)
void vel_kernel(float* __restrict__ ws, const float* __restrict__ params,
                const float* __restrict__ bdec, const float* __restrict__ amps,
                const int* __restrict__ sloc, int t) {
    int x = blockIdx.x * 64 + threadIdx.x;
    int y = blockIdx.y * 4 + threadIdx.y;
    int s = blockIdx.z;
    if (x >= NXP) return;

    float* F = ws + (size_t)s * 13 * FSTRIDE;
    float*       vy     = F + 0  * FSTRIDE;
    float*       vx     = F + 1  * FSTRIDE;
    const float* syy    = F + 2  * FSTRIDE;
    const float* sxx    = F + 3  * FSTRIDE;
    const float* sxy    = F + 4  * FSTRIDE;
    float*       msyy_y = F + 9  * FSTRIDE;
    float*       msxy_x = F + 10 * FSTRIDE;
    float*       msxy_y = F + 11 * FSTRIDE;
    float*       msxx_x = F + 12 * FSTRIDE;

    float by = bdec[y];
    float bx = bdec[NYP + x];
    int idx = y * PITCH + x;
    float buoy = params[3 * FSTRIDE + idx];

    float d, m;
    d = dpy(syy, y, x); m = by * msyy_y[idx] + (by - 1.0f) * d; msyy_y[idx] = m;
    float dsyy_dy = d + m;
    d = dmx(sxy, y, x); m = bx * msxy_x[idx] + (bx - 1.0f) * d; msxy_x[idx] = m;
    float dsxy_dx = d + m;
    float nvy = vy[idx] + DTC * buoy * (dsyy_dy + dsxy_dx);

    d = dmy(sxy, y, x); m = by * msxy_y[idx] + (by - 1.0f) * d; msxy_y[idx] = m;
    float dsxy_dy = d + m;
    d = dpx(sxx, y, x); m = bx * msxx_x[idx] + (bx - 1.0f) * d; msxx_x[idx] = m;
    float dsxx_dx = d + m;
    float nvx = vx[idx] + DTC * buoy * (dsxy_dy + dsxx_dx);

    // source injection (vy body force), NSRC == 1
    int sy = sloc[s * 2 + 0] + PML;
    int sx = sloc[s * 2 + 1] + PML;
    if (y == sy && x == sx) nvy += amps[s * NT + t];

    vy[idx] = nvy;
    vx[idx] = nvx;
}

__global__ __launch_bounds__(256)
void str_kernel(float* __restrict__ ws, const float* __restrict__ params,
                const float* __restrict__ bdec, const int* __restrict__ rloc,
                float* __restrict__ out, int t) {
    int x = blockIdx.x * 64 + threadIdx.x;
    int y = blockIdx.y * 4 + threadIdx.y;
    int s = blockIdx.z;

    float* F = ws + (size_t)s * 13 * FSTRIDE;
    const float* vy  = F + 0 * FSTRIDE;
    const float* vx  = F + 1 * FSTRIDE;
    float*       syy = F + 2 * FSTRIDE;
    float*       sxx = F + 3 * FSTRIDE;
    float*       sxy = F + 4 * FSTRIDE;
    float*       mvyy = F + 5 * FSTRIDE;
    float*       mvyx = F + 6 * FSTRIDE;
    float*       mvxy = F + 7 * FSTRIDE;
    float*       mvxx = F + 8 * FSTRIDE;

    // receiver extraction: vy is read-only in this kernel, safe to gather here
    if (blockIdx.x == 0 && blockIdx.y == 0) {
        int tid = threadIdx.y * 64 + threadIdx.x;
        if (tid < NREC) {
            int ry = rloc[(s * NREC + tid) * 2 + 0] + PML;
            int rx = rloc[(s * NREC + tid) * 2 + 1] + PML;
            out[(s * NREC + tid) * NT + t] = vy[ry * PITCH + rx];
        }
    }

    if (x >= NXP) return;

    float by = bdec[y];
    float bx = bdec[NYP + x];
    int idx = y * PITCH + x;
    float lam  = params[0 * FSTRIDE + idx];
    float lp2m = params[1 * FSTRIDE + idx];
    float muv  = params[2 * FSTRIDE + idx];

    float d, m;
    d = dmy(vy, y, x); m = by * mvyy[idx] + (by - 1.0f) * d; mvyy[idx] = m;
    float dvy_dy = d + m;
    d = dmx(vx, y, x); m = bx * mvxx[idx] + (bx - 1.0f) * d; mvxx[idx] = m;
    float dvx_dx = d + m;
    syy[idx] += DTC * (lp2m * dvy_dy + lam * dvx_dx);
    sxx[idx] += DTC * (lp2m * dvx_dx + lam * dvy_dy);

    d = dpx(vy, y, x); m = bx * mvyx[idx] + (bx - 1.0f) * d; mvyx[idx] = m;
    float dvy_dx = d + m;
    d = dpy(vx, y, x); m = by * mvxy[idx] + (by - 1.0f) * d; mvxy[idx] = m;
    float dvx_dy = d + m;
    sxy[idx] += DTC * muv * (dvy_dx + dvx_dy);
}

extern "C" void kernel_launch(void* const* d_in, const int* in_sizes, int n_in,
                              void* d_out, int out_size, void* d_ws, size_t ws_size,
                              hipStream_t stream) {
    const float* lamb = (const float*)d_in[0];
    const float* mu   = (const float*)d_in[1];
    const float* buo  = (const float*)d_in[2];
    const float* amps = (const float*)d_in[3];
    const int*   sloc = (const int*)d_in[4];
    const int*   rloc = (const int*)d_in[5];
    float* out = (float*)d_out;

    float* ws     = (float*)d_ws;
    float* state  = ws;                                   // 26 * FSTRIDE floats
    float* params = ws + (size_t)26 * FSTRIDE;            // 4 * FSTRIDE floats
    float* bdec   = ws + (size_t)30 * FSTRIDE;            // NYP + NXP floats

    // zero all state fields (ws is poisoned before every call)
    hipMemsetAsync(state, 0, (size_t)26 * FSTRIDE * sizeof(float), stream);

    dim3 pib(256, 1, 1), pig((NXP + 255) / 256, NYP, 1);
    init_params_kernel<<<pig, pib, 0, stream>>>(lamb, mu, buo, params);
    init_decay_kernel<<<(NYP + NXP + 255) / 256, 256, 0, stream>>>(bdec);

    dim3 blk(64, 4, 1);
    dim3 grd((NXP + 63) / 64, NYP / 4, NSHOT);
    for (int t = 0; t < NT; ++t) {
        vel_kernel<<<grd, blk, 0, stream>>>(state, params, bdec, amps, sloc, t);
        str_kernel<<<grd, blk, 0, stream>>>(state, params, bdec, rloc, out, t);
    }
}